// Round 19
// baseline (126.354 us; speedup 1.0000x reference)
//
#include <hip/hip_runtime.h>

typedef __attribute__((ext_vector_type(8))) short bf16x8;
typedef __attribute__((ext_vector_type(16))) float f32x16;

#define BATCH 2
#define SEQ 2048
#define DMODEL 768
#define NH 12
#define HD 64
#define M_TOK (BATCH * SEQ)   /* 4096 */
#define N_KQV (3 * DMODEL)    /* 2304 */
#define BH_TOT (BATCH * NH)   /* 24 */

#define GLOAD16(gsrc, ldst) __builtin_amdgcn_global_load_lds( \
    (const __attribute__((address_space(1))) unsigned int*)(const void*)(gsrc), \
    (__attribute__((address_space(3))) unsigned int*)(void*)(ldst), 16, 0, 0)

__device__ __forceinline__ unsigned short f2bf(float f) {
  unsigned int u = __float_as_uint(f);
  u += 0x7FFFu + ((u >> 16) & 1u);
  return (unsigned short)(u >> 16);
}

__device__ __forceinline__ unsigned int cvtpk(float lo, float hi) {
  unsigned int r;
  asm("v_cvt_pk_bf16_f32 %0, %1, %2" : "=v"(r) : "v"(lo), "v"(hi));
  return r;
}

// ---------------- merged prep kernel ----------------
// job A: x f32->bf16; job B/C: weight transpose-cvt; job D: zero O_acc/l_acc
#define NB_CVT 3072                       /* 4096*768/4/256 */
#define NB_T1 (72 * 24)
#define NB_T2 (24 * 24)
#define NFLOAT_ACC (BH_TOT * SEQ * HD + BH_TOT * SEQ)   /* 3194880 */
#define NB_Z (NFLOAT_ACC / 4 / 256)                      /* 3120 */

__global__ __launch_bounds__(256) void prep_kernel(
    const float* __restrict__ x, unsigned short* __restrict__ x_bf,
    const float* __restrict__ Wkqv, unsigned short* __restrict__ wkqvT,
    const float* __restrict__ Wproj, unsigned short* __restrict__ wprojT,
    float* __restrict__ acc_zero) {
  const int b = blockIdx.x;
  if (b < NB_CVT) {
    int i = b * 256 + threadIdx.x;
    float4 v = reinterpret_cast<const float4*>(x)[i];
    unsigned long long p = (unsigned long long)f2bf(v.x)
                         | ((unsigned long long)f2bf(v.y) << 16)
                         | ((unsigned long long)f2bf(v.z) << 32)
                         | ((unsigned long long)f2bf(v.w) << 48);
    reinterpret_cast<unsigned long long*>(x_bf)[i] = p;
    return;
  }
  if (b >= NB_CVT + NB_T1 + NB_T2) {  // job D: zero accumulators
    int i = (b - NB_CVT - NB_T1 - NB_T2) * 256 + threadIdx.x;
    reinterpret_cast<float4*>(acc_zero)[i] = (float4){0.f, 0.f, 0.f, 0.f};
    return;
  }
  __shared__ float tile[32][33];
  const float* in;
  unsigned short* out;
  int rows, cols, bx, by;
  if (b < NB_CVT + NB_T1) {
    int j = b - NB_CVT;
    in = Wkqv; out = wkqvT; rows = DMODEL; cols = N_KQV;
    bx = j % 72; by = j / 72;
  } else {
    int j = b - NB_CVT - NB_T1;
    in = Wproj; out = wprojT; rows = DMODEL; cols = DMODEL;
    bx = j % 24; by = j / 24;
  }
  const int tx = threadIdx.x & 31, ty = threadIdx.x >> 5;
  int c0 = bx * 32, r0 = by * 32;
  for (int i = ty; i < 32; i += 8)
    tile[i][tx] = in[(size_t)(r0 + i) * cols + c0 + tx];
  __syncthreads();
  for (int i = ty; i < 32; i += 8)
    out[(size_t)(c0 + i) * rows + r0 + tx] = f2bf(tile[tx][i]);
}

// ---------------- WAVE-INDEPENDENT GEMM (round-18 verified) ----------------
template <int NBX, int MODE>
__global__ __launch_bounds__(64) void gemm_wi(
    const unsigned short* __restrict__ A,
    const unsigned short* __restrict__ BT,
    const float* __restrict__ bias,
    int NTOT,
    unsigned short* __restrict__ outK, unsigned short* __restrict__ outQ,
    unsigned short* __restrict__ outVT, float* __restrict__ outF) {
  constexpr int K = DMODEL;
  __shared__ __align__(16) unsigned short lds_a[2][64][32];
  __shared__ __align__(16) unsigned short lds_b[2][64][32];
  const int lane = threadIdx.x & 63;
  const int l31 = lane & 31, hi = lane >> 5;

  const int fid = (int)blockIdx.x;
  const int xcd = fid & 7, slot = fid >> 3;
  const int by = xcd * 8 + (slot & 7);
  const int bx = slot >> 3;
  const int m0 = by * 64, n0 = bx * 64;

  f32x16 acc[2][2];
#pragma unroll
  for (int mi = 0; mi < 2; mi++)
#pragma unroll
    for (int nj = 0; nj < 2; nj++)
#pragma unroll
      for (int i = 0; i < 16; i++) acc[mi][nj][i] = 0.f;

  const int srow = lane >> 2;
  const int sg = ((lane & 3) ^ ((lane >> 3) & 3)) * 8;
  const int xq = (l31 >> 1) & 3;

#define STAGE(buf, k0)                                                        \
  {                                                                           \
    _Pragma("unroll")                                                         \
    for (int rr = 0; rr < 4; ++rr)                                            \
      GLOAD16(&A[(size_t)(m0 + rr * 16 + srow) * K + (k0) + sg],              \
              &lds_a[buf][rr * 16][0]);                                       \
    _Pragma("unroll")                                                         \
    for (int rr = 0; rr < 4; ++rr)                                            \
      GLOAD16(&BT[(size_t)(n0 + rr * 16 + srow) * K + (k0) + sg],             \
              &lds_b[buf][rr * 16][0]);                                       \
  }

  const int KT = K >> 5;
  STAGE(0, 0);
  STAGE(1, 32);

  for (int kt = 0; kt < KT; ++kt) {
    const int cur = kt & 1;
    if (kt + 1 < KT) asm volatile("s_waitcnt vmcnt(8)" ::: "memory");
    else             asm volatile("s_waitcnt vmcnt(0)" ::: "memory");
    __builtin_amdgcn_sched_barrier(0);

    bf16x8 aA[2][2], aB[2][2];
#pragma unroll
    for (int ds = 0; ds < 2; ds++) {
      const int rc = ((ds * 2 + hi) ^ xq) * 8;
#pragma unroll
      for (int mi = 0; mi < 2; mi++)
        aA[ds][mi] = *(const bf16x8*)&lds_a[cur][mi * 32 + l31][rc];
#pragma unroll
      for (int nj = 0; nj < 2; nj++)
        aB[ds][nj] = *(const bf16x8*)&lds_b[cur][nj * 32 + l31][rc];
    }
#pragma unroll
    for (int ds = 0; ds < 2; ds++)
#pragma unroll
      for (int mi = 0; mi < 2; mi++)
#pragma unroll
        for (int nj = 0; nj < 2; nj++)
          acc[mi][nj] = __builtin_amdgcn_mfma_f32_32x32x16_bf16(
              aA[ds][mi], aB[ds][nj], acc[mi][nj], 0, 0, 0);

    if (kt + 2 < KT) {
      asm volatile("s_waitcnt lgkmcnt(0)" ::: "memory");
      __builtin_amdgcn_sched_barrier(0);
      STAGE(cur, (kt + 2) << 5);
    }
  }
#undef STAGE

#pragma unroll
  for (int mi = 0; mi < 2; mi++) {
#pragma unroll
    for (int nj = 0; nj < 2; nj++) {
#pragma unroll
      for (int r = 0; r < 16; r++) {
        int row = m0 + mi * 32 + (r & 3) + 8 * (r >> 2) + 4 * hi;
        int col = n0 + nj * 32 + l31;
        float v = acc[mi][nj][r] + bias[col];
        if (MODE == 0) {
          int chunk = col / DMODEL;
          int d = col - chunk * DMODEL;
          int hh = d >> 6, di = d & 63;
          int bb = row >> 11, tok = row & 2047;
          int bh = bb * NH + hh;
          if (chunk == 0)
            outK[((size_t)bh * SEQ + tok) * HD + di] = f2bf(v);
          else if (chunk == 1)
            outQ[((size_t)bh * SEQ + tok) * HD + di] = f2bf(v * 0.125f);
          else
            outVT[((size_t)bh * HD + di) * SEQ + tok] = f2bf(v);
        } else {
          outF[(size_t)row * NTOT + col] = v;
        }
      }
    }
  }
}

// ---------------- flash attention: KV-SPLIT (chunks of 8 k-tiles) ----------------
// Fixed-shift softmax => partials are PURE SUMS: each (head, q-tile, chunk)
// block atomicAdds merged O/l into f32 accumulators; finalize divides.
// 3840 near-uniform blocks (<=8 iters each), XCD-affine, backfilled.
// Loop body / staging / softmax / pack byte-identical to round-8 verified.
__global__ __launch_bounds__(128) void attn_kernel(
    const unsigned short* __restrict__ qbuf,  // [BH][SEQ][HD], pre-scaled
    const unsigned short* __restrict__ kbuf,  // [BH][SEQ][HD]
    const unsigned short* __restrict__ vT,    // [BH][HD][SEQ]
    float* __restrict__ O_acc,                // [BH][SEQ][HD] f32 (zeroed)
    float* __restrict__ l_acc) {              // [BH][SEQ] f32 (zeroed)
  __shared__ __align__(16) char smem_raw[18432];
  auto k_lds = reinterpret_cast<unsigned short (*)[72]>(smem_raw);
  auto v_lds = reinterpret_cast<unsigned short (*)[72]>(smem_raw + 9216);
  auto o_merge = reinterpret_cast<float (*)[32][33]>(smem_raw);
  auto l_merge = reinterpret_cast<float (*)[32]>(smem_raw + 9216);

  const int tid = threadIdx.x, lane = tid & 63, w = tid >> 6;
  const int l31 = lane & 31, hi = lane >> 5;

  // decode: fid%8=XCD, 3 heads/XCD; s in [0,160) -> (chunk c, q-tile t)
  const int fid = (int)blockIdx.x;                // 0..3839
  const int xcd = fid & 7, slot = fid >> 3;       // 0..479
  const int head3 = slot % 3;
  const int s = slot / 3;                         // 0..159
  int c, r_;
  if (s < 64)       { c = 0; r_ = s; }
  else if (s < 112) { c = 1; r_ = s - 64; }
  else if (s < 144) { c = 2; r_ = s - 112; }
  else              { c = 3; r_ = s - 144; }
  const int t = 63 - r_;                          // q-tile (32 rows)
  const int bh = head3 * 8 + xcd;
  const int ktmax = t >> 1;                       // last k-tile (diag)
  const int kt0 = c * 8;
  const int kt_end = (kt0 + 7 < ktmax) ? kt0 + 7 : ktmax;

  const size_t qk_base = (size_t)bh * SEQ * HD;
  const size_t v_base = (size_t)bh * HD * SEQ;

  const int sr = w * 32 + (lane >> 3);
  const int sc = (lane & 7) * 8;

  {  // prologue: stage k-tile kt0
    bf16x8 rk[4], rv[4];
#pragma unroll
    for (int p = 0; p < 4; p++) {
      rk[p] = *(const bf16x8*)&kbuf[qk_base + (size_t)(kt0 * 64 + sr + 8 * p) * HD + sc];
      rv[p] = *(const bf16x8*)&vT[v_base + (size_t)(sr + 8 * p) * SEQ + kt0 * 64 + sc];
    }
#pragma unroll
    for (int p = 0; p < 4; p++) {
      *(bf16x8*)&k_lds[sr + 8 * p][sc] = rk[p];
      *(bf16x8*)&v_lds[sr + 8 * p][sc] = rv[p];
    }
  }

  bf16x8 aq[4];
#pragma unroll
  for (int ds = 0; ds < 4; ds++)
    aq[ds] = *(const bf16x8*)&qbuf[qk_base + (size_t)(t * 32 + l31) * HD + ds * 16 + hi * 8];

  f32x16 o0, o1;
#pragma unroll
  for (int i = 0; i < 16; i++) { o0[i] = 0.f; o1[i] = 0.f; }
  float lsum = 0.f;

  __syncthreads();

  for (int kt = kt0; kt <= kt_end; ++kt) {
    const bool more = (kt < kt_end);
    bf16x8 rk[4], rv[4];
    if (more) {
      const int nrow = (kt + 1) * 64;
#pragma unroll
      for (int p = 0; p < 4; p++) {
        rk[p] = *(const bf16x8*)&kbuf[qk_base + (size_t)(nrow + sr + 8 * p) * HD + sc];
        rv[p] = *(const bf16x8*)&vT[v_base + (size_t)(sr + 8 * p) * SEQ + nrow + sc];
      }
    }

    f32x16 sv;
#pragma unroll
    for (int i = 0; i < 16; i++) sv[i] = 0.f;
    __builtin_amdgcn_s_setprio(1);
#pragma unroll
    for (int ds = 0; ds < 4; ds++) {
      bf16x8 bk = *(const bf16x8*)&k_lds[w * 32 + l31][ds * 16 + hi * 8];
      sv = __builtin_amdgcn_mfma_f32_32x32x16_bf16(bk, aq[ds], sv, 0, 0, 0);
    }
    __builtin_amdgcn_s_setprio(0);

    const bool diag = (kt == ktmax);
    const int qb2 = (t & 1) * 32;
#pragma unroll
    for (int r = 0; r < 16; r++) {
      int kr = (r & 3) + 8 * (r >> 2) + 4 * hi;
      float val = sv[r];
      if (diag && (w * 32 + kr > qb2 + l31)) val = -1e30f;
      float p = __expf(val);
      sv[r] = p;
      lsum += p;
    }

    union { unsigned int u[4]; bf16x8 v; } f1, f2;
    {
      unsigned int A = cvtpk(sv[0], sv[1]), B = cvtpk(sv[2], sv[3]);
      unsigned int C = cvtpk(sv[4], sv[5]), D = cvtpk(sv[6], sv[7]);
      auto rAC = __builtin_amdgcn_permlane32_swap(A, C, false, false);
      auto rBD = __builtin_amdgcn_permlane32_swap(B, D, false, false);
      f1.u[0] = rAC[0]; f1.u[1] = rBD[0]; f1.u[2] = rAC[1]; f1.u[3] = rBD[1];
      unsigned int A2 = cvtpk(sv[8], sv[9]),   B2 = cvtpk(sv[10], sv[11]);
      unsigned int C2 = cvtpk(sv[12], sv[13]), D2 = cvtpk(sv[14], sv[15]);
      auto rAC2 = __builtin_amdgcn_permlane32_swap(A2, C2, false, false);
      auto rBD2 = __builtin_amdgcn_permlane32_swap(B2, D2, false, false);
      f2.u[0] = rAC2[0]; f2.u[1] = rBD2[0]; f2.u[2] = rAC2[1]; f2.u[3] = rBD2[1];
    }

    __builtin_amdgcn_s_setprio(1);
    {
      bf16x8 bv00 = *(const bf16x8*)&v_lds[l31][w * 32 + hi * 8];
      bf16x8 bv01 = *(const bf16x8*)&v_lds[32 + l31][w * 32 + hi * 8];
      o0 = __builtin_amdgcn_mfma_f32_32x32x16_bf16(f1.v, bv00, o0, 0, 0, 0);
      o1 = __builtin_amdgcn_mfma_f32_32x32x16_bf16(f1.v, bv01, o1, 0, 0, 0);
      bf16x8 bv10 = *(const bf16x8*)&v_lds[l31][w * 32 + 16 + hi * 8];
      bf16x8 bv11 = *(const bf16x8*)&v_lds[32 + l31][w * 32 + 16 + hi * 8];
      o0 = __builtin_amdgcn_mfma_f32_32x32x16_bf16(f2.v, bv10, o0, 0, 0, 0);
      o1 = __builtin_amdgcn_mfma_f32_32x32x16_bf16(f2.v, bv11, o1, 0, 0, 0);
    }
    __builtin_amdgcn_s_setprio(0);

    if (more) {
      __syncthreads();
#pragma unroll
      for (int p = 0; p < 4; p++) {
        *(bf16x8*)&k_lds[sr + 8 * p][sc] = rk[p];
        *(bf16x8*)&v_lds[sr + 8 * p][sc] = rv[p];
      }
      __syncthreads();
    }
  }

  // ---- cross-wave merge (verified) then atomic accumulate ----
  __syncthreads();
  {
    float ltot = lsum + __shfl_xor(lsum, 32);
    if (hi == 0) l_merge[w][l31] = ltot;
    f32x16 osend = w ? o0 : o1;
#pragma unroll
    for (int r = 0; r < 16; r++) {
      int ql = (r & 3) + 8 * (r >> 2) + 4 * hi;
      o_merge[w][ql][l31] = osend[r];
    }
    __syncthreads();
    f32x16 okeep = w ? o1 : o0;
#pragma unroll
    for (int r = 0; r < 16; r++) {
      int ql = (r & 3) + 8 * (r >> 2) + 4 * hi;
      float ot = okeep[r] + o_merge[1 - w][ql][l31];
      atomicAdd(&O_acc[((size_t)bh * SEQ + t * 32 + ql) * HD + w * 32 + l31], ot);
      if (w == 0 && l31 == 0) {
        float lt = l_merge[0][ql] + l_merge[1][ql];
        atomicAdd(&l_acc[(size_t)bh * SEQ + t * 32 + ql], lt);
      }
    }
  }
}

// ---------------- finalize: sa = bf16(O_acc / l_acc) ----------------
__global__ __launch_bounds__(256) void attn_finalize(
    const float* __restrict__ O_acc, const float* __restrict__ l_acc,
    unsigned short* __restrict__ sa) {
  int e = blockIdx.x * 256 + threadIdx.x;        // [BH][SEQ][HD] linear
  int d = e & 63;
  int row = (e >> 6) & 2047;
  int bh = e >> 17;
  int bb = bh / NH, h = bh - bb * NH;
  float v = O_acc[e] / l_acc[bh * SEQ + row];
  sa[((size_t)bb * SEQ + row) * DMODEL + h * HD + d] = f2bf(v);
}

// ---------------- launch ----------------

extern "C" void kernel_launch(void* const* d_in, const int* in_sizes, int n_in,
                              void* d_out, int out_size, void* d_ws, size_t ws_size,
                              hipStream_t stream) {
  const float* x     = (const float*)d_in[0];
  const float* Wkqv  = (const float*)d_in[1];
  const float* bkqv  = (const float*)d_in[2];
  const float* Wproj = (const float*)d_in[3];
  const float* bproj = (const float*)d_in[4];
  float* out = (float*)d_out;

  char* ws = (char*)d_ws;
  unsigned short* x_bf   = (unsigned short*)(ws + 0);
  unsigned short* wkqvT  = (unsigned short*)(ws + 6291456);
  unsigned short* wprojT = (unsigned short*)(ws + 9830400);
  unsigned short* qb     = (unsigned short*)(ws + 11010048);
  unsigned short* kb     = (unsigned short*)(ws + 17301504);
  unsigned short* vT     = (unsigned short*)(ws + 23592960);
  unsigned short* sa     = (unsigned short*)(ws + 29884416);  // 6.3 MB
  float* O_acc           = (float*)(ws + 36175872);           // 12.6 MB
  float* l_acc           = (float*)(ws + 48758784);           // 0.2 MB -> 48.9 MB total

  prep_kernel<<<NB_CVT + NB_T1 + NB_T2 + NB_Z, 256, 0, stream>>>(
      x, x_bf, Wkqv, wkqvT, Wproj, wprojT, O_acc);

  gemm_wi<N_KQV / 64, 0><<<2304, 64, 0, stream>>>(
      x_bf, wkqvT, bkqv, N_KQV, kb, qb, vT, nullptr);

  attn_kernel<<<3840, 128, 0, stream>>>(qb, kb, vT, O_acc, l_acc);

  attn_finalize<<<BH_TOT * SEQ * HD / 256, 256, 0, stream>>>(O_acc, l_acc, sa);

  gemm_wi<DMODEL / 64, 1><<<768, 64, 0, stream>>>(
      sa, wprojT, bproj, DMODEL, nullptr, nullptr, nullptr, out);
}

// Round 20
// 98.524 us; speedup vs baseline: 1.2825x; 1.2825x over previous
//
#include <hip/hip_runtime.h>

typedef __attribute__((ext_vector_type(8))) short bf16x8;
typedef __attribute__((ext_vector_type(16))) float f32x16;

#define BATCH 2
#define SEQ 2048
#define DMODEL 768
#define NH 12
#define HD 64
#define M_TOK (BATCH * SEQ)   /* 4096 */
#define N_KQV (3 * DMODEL)    /* 2304 */

#define GLOAD16(gsrc, ldst) __builtin_amdgcn_global_load_lds( \
    (const __attribute__((address_space(1))) unsigned int*)(const void*)(gsrc), \
    (__attribute__((address_space(3))) unsigned int*)(void*)(ldst), 16, 0, 0)

__device__ __forceinline__ unsigned short f2bf(float f) {
  unsigned int u = __float_as_uint(f);
  u += 0x7FFFu + ((u >> 16) & 1u);
  return (unsigned short)(u >> 16);
}

__device__ __forceinline__ unsigned int cvtpk(float lo, float hi) {
  unsigned int r;
  asm("v_cvt_pk_bf16_f32 %0, %1, %2" : "=v"(r) : "v"(lo), "v"(hi));
  return r;
}

// ---------------- merged prep kernel ----------------
#define NB_CVT 3072                       /* 4096*768/4/256 */
#define NB_T1 (72 * 24)                   /* 2304/32 x 768/32 */
#define NB_T2 (24 * 24)                   /* 768/32 x 768/32 */

__global__ __launch_bounds__(256) void prep_kernel(
    const float* __restrict__ x, unsigned short* __restrict__ x_bf,
    const float* __restrict__ Wkqv, unsigned short* __restrict__ wkqvT,
    const float* __restrict__ Wproj, unsigned short* __restrict__ wprojT) {
  const int b = blockIdx.x;
  if (b < NB_CVT) {
    int i = b * 256 + threadIdx.x;
    float4 v = reinterpret_cast<const float4*>(x)[i];
    unsigned long long p = (unsigned long long)f2bf(v.x)
                         | ((unsigned long long)f2bf(v.y) << 16)
                         | ((unsigned long long)f2bf(v.z) << 32)
                         | ((unsigned long long)f2bf(v.w) << 48);
    reinterpret_cast<unsigned long long*>(x_bf)[i] = p;
    return;
  }
  __shared__ float tile[32][33];
  const float* in;
  unsigned short* out;
  int rows, cols, bx, by;
  if (b < NB_CVT + NB_T1) {
    int j = b - NB_CVT;
    in = Wkqv; out = wkqvT; rows = DMODEL; cols = N_KQV;
    bx = j % 72; by = j / 72;
  } else {
    int j = b - NB_CVT - NB_T1;
    in = Wproj; out = wprojT; rows = DMODEL; cols = DMODEL;
    bx = j % 24; by = j / 24;
  }
  const int tx = threadIdx.x & 31, ty = threadIdx.x >> 5;  // 32 x 8
  int c0 = bx * 32, r0 = by * 32;
  for (int i = ty; i < 32; i += 8)
    tile[i][tx] = in[(size_t)(r0 + i) * cols + c0 + tx];
  __syncthreads();
  for (int i = ty; i < 32; i += 8)
    out[(size_t)(c0 + i) * rows + r0 + tx] = f2bf(tile[tx][i]);
}

// ---------------- WAVE-INDEPENDENT GEMM: 1 wave per 64x64 tile ----------------
// Block = 64 threads (one wave), PRIVATE double-buffered LDS (16 KB), ZERO
// barriers, counted per-wave vmcnt. Round-18 verified (gemm1 40.6us).
template <int NBX, int MODE>
__global__ __launch_bounds__(64) void gemm_wi(
    const unsigned short* __restrict__ A,   // [M][K] bf16
    const unsigned short* __restrict__ BT,  // [N][K] bf16
    const float* __restrict__ bias,
    int NTOT,                               // MODE1 output row stride
    unsigned short* __restrict__ outK, unsigned short* __restrict__ outQ,
    unsigned short* __restrict__ outVT, float* __restrict__ outF) {
  constexpr int K = DMODEL;
  __shared__ __align__(16) unsigned short lds_a[2][64][32];
  __shared__ __align__(16) unsigned short lds_b[2][64][32];
  const int lane = threadIdx.x & 63;
  const int l31 = lane & 31, hi = lane >> 5;

  // XCD-affine decode: fid%8 = XCD; each XCD owns 8 consecutive by values
  const int fid = (int)blockIdx.x;
  const int xcd = fid & 7, slot = fid >> 3;
  const int by = xcd * 8 + (slot & 7);
  const int bx = slot >> 3;               // 0..NBX-1
  const int m0 = by * 64, n0 = bx * 64;

  f32x16 acc[2][2];
#pragma unroll
  for (int mi = 0; mi < 2; mi++)
#pragma unroll
    for (int nj = 0; nj < 2; nj++)
#pragma unroll
      for (int i = 0; i < 16; i++) acc[mi][nj][i] = 0.f;

  const int srow = lane >> 2;                               // 0..15
  const int sg = ((lane & 3) ^ ((lane >> 3) & 3)) * 8;      // swizzled global k-chunk
  const int xq = (l31 >> 1) & 3;                            // read-side XOR

#define STAGE(buf, k0)                                                        \
  {                                                                           \
    _Pragma("unroll")                                                         \
    for (int rr = 0; rr < 4; ++rr)                                            \
      GLOAD16(&A[(size_t)(m0 + rr * 16 + srow) * K + (k0) + sg],              \
              &lds_a[buf][rr * 16][0]);                                       \
    _Pragma("unroll")                                                         \
    for (int rr = 0; rr < 4; ++rr)                                            \
      GLOAD16(&BT[(size_t)(n0 + rr * 16 + srow) * K + (k0) + sg],             \
              &lds_b[buf][rr * 16][0]);                                       \
  }

  const int KT = K >> 5;   // 24
  STAGE(0, 0);
  STAGE(1, 32);

  for (int kt = 0; kt < KT; ++kt) {
    const int cur = kt & 1;
    if (kt + 1 < KT) asm volatile("s_waitcnt vmcnt(8)" ::: "memory");
    else             asm volatile("s_waitcnt vmcnt(0)" ::: "memory");
    __builtin_amdgcn_sched_barrier(0);

    bf16x8 aA[2][2], aB[2][2];
#pragma unroll
    for (int ds = 0; ds < 2; ds++) {
      const int rc = ((ds * 2 + hi) ^ xq) * 8;   // swizzled read chunk
#pragma unroll
      for (int mi = 0; mi < 2; mi++)
        aA[ds][mi] = *(const bf16x8*)&lds_a[cur][mi * 32 + l31][rc];
#pragma unroll
      for (int nj = 0; nj < 2; nj++)
        aB[ds][nj] = *(const bf16x8*)&lds_b[cur][nj * 32 + l31][rc];
    }
#pragma unroll
    for (int ds = 0; ds < 2; ds++)
#pragma unroll
      for (int mi = 0; mi < 2; mi++)
#pragma unroll
        for (int nj = 0; nj < 2; nj++)
          acc[mi][nj] = __builtin_amdgcn_mfma_f32_32x32x16_bf16(
              aA[ds][mi], aB[ds][nj], acc[mi][nj], 0, 0, 0);

    // within-wave WAR: drain ds_reads before overwriting the buffer
    if (kt + 2 < KT) {
      asm volatile("s_waitcnt lgkmcnt(0)" ::: "memory");
      __builtin_amdgcn_sched_barrier(0);
      STAGE(cur, (kt + 2) << 5);
    }
  }
#undef STAGE

#pragma unroll
  for (int mi = 0; mi < 2; mi++) {
#pragma unroll
    for (int nj = 0; nj < 2; nj++) {
#pragma unroll
      for (int r = 0; r < 16; r++) {
        int row = m0 + mi * 32 + (r & 3) + 8 * (r >> 2) + 4 * hi;
        int col = n0 + nj * 32 + l31;
        float v = acc[mi][nj][r] + bias[col];
        if (MODE == 0) {
          int chunk = col / DMODEL;          // 0=k, 1=q, 2=v
          int d = col - chunk * DMODEL;
          int hh = d >> 6, di = d & 63;
          int bb = row >> 11, tok = row & 2047;
          int bh = bb * NH + hh;
          if (chunk == 0)
            outK[((size_t)bh * SEQ + tok) * HD + di] = f2bf(v);
          else if (chunk == 1)
            outQ[((size_t)bh * SEQ + tok) * HD + di] = f2bf(v * 0.125f);
          else
            outVT[((size_t)bh * HD + di) * SEQ + tok] = f2bf(v);
        } else {
          outF[(size_t)row * NTOT + col] = v;
        }
      }
    }
  }
}

// ---------------- flash attention (round-8 verified; t-major order) ----------------
__global__ __launch_bounds__(128) void attn_kernel(
    const unsigned short* __restrict__ qbuf,  // [BH][SEQ][HD], pre-scaled by 1/8
    const unsigned short* __restrict__ kbuf,  // [BH][SEQ][HD]
    const unsigned short* __restrict__ vT,    // [BH][HD][SEQ]
    unsigned short* __restrict__ sa) {        // [B][SEQ][DMODEL]
  __shared__ __align__(16) char smem_raw[18432];
  auto k_lds = reinterpret_cast<unsigned short (*)[72]>(smem_raw);
  auto v_lds = reinterpret_cast<unsigned short (*)[72]>(smem_raw + 9216);
  auto o_merge = reinterpret_cast<float (*)[32][33]>(smem_raw);
  auto l_merge = reinterpret_cast<float (*)[32]>(smem_raw + 9216);

  const int tid = threadIdx.x, lane = tid & 63, w = tid >> 6;
  const int l31 = lane & 31, hi = lane >> 5;

  const int fid = (int)blockIdx.y * (int)gridDim.x + (int)blockIdx.x;  // 0..1535
  const int xcd = fid & 7, slot = fid >> 3;       // slot 0..191
  const int head3 = slot % 3;
  const int t = 63 - slot / 3;                    // 32-row q-tile, longest first
  const int bh = head3 * 8 + xcd;                 // 0..23
  const int ktmax = t >> 1;

  const size_t qk_base = (size_t)bh * SEQ * HD;
  const size_t v_base = (size_t)bh * HD * SEQ;
  const int bb = bh / NH, h = bh - bb * NH;

  const int sr = w * 32 + (lane >> 3);
  const int sc = (lane & 7) * 8;

  {
    bf16x8 rk[4], rv[4];
#pragma unroll
    for (int p = 0; p < 4; p++) {
      rk[p] = *(const bf16x8*)&kbuf[qk_base + (size_t)(sr + 8 * p) * HD + sc];
      rv[p] = *(const bf16x8*)&vT[v_base + (size_t)(sr + 8 * p) * SEQ + sc];
    }
#pragma unroll
    for (int p = 0; p < 4; p++) {
      *(bf16x8*)&k_lds[sr + 8 * p][sc] = rk[p];
      *(bf16x8*)&v_lds[sr + 8 * p][sc] = rv[p];
    }
  }

  bf16x8 aq[4];
#pragma unroll
  for (int ds = 0; ds < 4; ds++)
    aq[ds] = *(const bf16x8*)&qbuf[qk_base + (size_t)(t * 32 + l31) * HD + ds * 16 + hi * 8];

  f32x16 o0, o1;
#pragma unroll
  for (int i = 0; i < 16; i++) { o0[i] = 0.f; o1[i] = 0.f; }
  float lsum = 0.f;

  __syncthreads();

  for (int kt = 0; kt <= ktmax; ++kt) {
    const bool more = (kt < ktmax);
    bf16x8 rk[4], rv[4];
    if (more) {
      const int nrow = (kt + 1) * 64;
#pragma unroll
      for (int p = 0; p < 4; p++) {
        rk[p] = *(const bf16x8*)&kbuf[qk_base + (size_t)(nrow + sr + 8 * p) * HD + sc];
        rv[p] = *(const bf16x8*)&vT[v_base + (size_t)(sr + 8 * p) * SEQ + nrow + sc];
      }
    }

    f32x16 s;
#pragma unroll
    for (int i = 0; i < 16; i++) s[i] = 0.f;
    __builtin_amdgcn_s_setprio(1);
#pragma unroll
    for (int ds = 0; ds < 4; ds++) {
      bf16x8 bk = *(const bf16x8*)&k_lds[w * 32 + l31][ds * 16 + hi * 8];
      s = __builtin_amdgcn_mfma_f32_32x32x16_bf16(bk, aq[ds], s, 0, 0, 0);
    }
    __builtin_amdgcn_s_setprio(0);

    const bool diag = (kt == ktmax);
    const int qb2 = (t & 1) * 32;
#pragma unroll
    for (int r = 0; r < 16; r++) {
      int kr = (r & 3) + 8 * (r >> 2) + 4 * hi;
      float val = s[r];
      if (diag && (w * 32 + kr > qb2 + l31)) val = -1e30f;
      float p = __expf(val);
      s[r] = p;
      lsum += p;
    }

    union { unsigned int u[4]; bf16x8 v; } f1, f2;
    {
      unsigned int A = cvtpk(s[0], s[1]), B = cvtpk(s[2], s[3]);
      unsigned int C = cvtpk(s[4], s[5]), D = cvtpk(s[6], s[7]);
      auto rAC = __builtin_amdgcn_permlane32_swap(A, C, false, false);
      auto rBD = __builtin_amdgcn_permlane32_swap(B, D, false, false);
      f1.u[0] = rAC[0]; f1.u[1] = rBD[0]; f1.u[2] = rAC[1]; f1.u[3] = rBD[1];
      unsigned int A2 = cvtpk(s[8], s[9]),   B2 = cvtpk(s[10], s[11]);
      unsigned int C2 = cvtpk(s[12], s[13]), D2 = cvtpk(s[14], s[15]);
      auto rAC2 = __builtin_amdgcn_permlane32_swap(A2, C2, false, false);
      auto rBD2 = __builtin_amdgcn_permlane32_swap(B2, D2, false, false);
      f2.u[0] = rAC2[0]; f2.u[1] = rBD2[0]; f2.u[2] = rAC2[1]; f2.u[3] = rBD2[1];
    }

    __builtin_amdgcn_s_setprio(1);
    {
      bf16x8 bv00 = *(const bf16x8*)&v_lds[l31][w * 32 + hi * 8];
      bf16x8 bv01 = *(const bf16x8*)&v_lds[32 + l31][w * 32 + hi * 8];
      o0 = __builtin_amdgcn_mfma_f32_32x32x16_bf16(f1.v, bv00, o0, 0, 0, 0);
      o1 = __builtin_amdgcn_mfma_f32_32x32x16_bf16(f1.v, bv01, o1, 0, 0, 0);
      bf16x8 bv10 = *(const bf16x8*)&v_lds[l31][w * 32 + 16 + hi * 8];
      bf16x8 bv11 = *(const bf16x8*)&v_lds[32 + l31][w * 32 + 16 + hi * 8];
      o0 = __builtin_amdgcn_mfma_f32_32x32x16_bf16(f2.v, bv10, o0, 0, 0, 0);
      o1 = __builtin_amdgcn_mfma_f32_32x32x16_bf16(f2.v, bv11, o1, 0, 0, 0);
    }
    __builtin_amdgcn_s_setprio(0);

    if (more) {
      __syncthreads();
#pragma unroll
      for (int p = 0; p < 4; p++) {
        *(bf16x8*)&k_lds[sr + 8 * p][sc] = rk[p];
        *(bf16x8*)&v_lds[sr + 8 * p][sc] = rv[p];
      }
      __syncthreads();
    }
  }

  __syncthreads();
  {
    float ltot = lsum + __shfl_xor(lsum, 32);
    if (hi == 0) l_merge[w][l31] = ltot;
    f32x16 osend = w ? o0 : o1;
#pragma unroll
    for (int r = 0; r < 16; r++) {
      int ql = (r & 3) + 8 * (r >> 2) + 4 * hi;
      o_merge[w][ql][l31] = osend[r];
    }
    __syncthreads();
    f32x16 okeep = w ? o1 : o0;
#pragma unroll
    for (int r = 0; r < 16; r++) {
      int ql = (r & 3) + 8 * (r >> 2) + 4 * hi;
      float ot = okeep[r] + o_merge[1 - w][ql][l31];
      float lt = l_merge[0][ql] + l_merge[1][ql];
      sa[((size_t)bb * SEQ + t * 32 + ql) * DMODEL + h * HD + w * 32 + l31] = f2bf(ot / lt);
    }
  }
}

// ---------------- launch ----------------

extern "C" void kernel_launch(void* const* d_in, const int* in_sizes, int n_in,
                              void* d_out, int out_size, void* d_ws, size_t ws_size,
                              hipStream_t stream) {
  const float* x     = (const float*)d_in[0];
  const float* Wkqv  = (const float*)d_in[1];
  const float* bkqv  = (const float*)d_in[2];
  const float* Wproj = (const float*)d_in[3];
  const float* bproj = (const float*)d_in[4];
  float* out = (float*)d_out;

  char* ws = (char*)d_ws;
  unsigned short* x_bf   = (unsigned short*)(ws + 0);
  unsigned short* wkqvT  = (unsigned short*)(ws + 6291456);
  unsigned short* wprojT = (unsigned short*)(ws + 9830400);
  unsigned short* qb     = (unsigned short*)(ws + 11010048);
  unsigned short* kb     = (unsigned short*)(ws + 17301504);
  unsigned short* vT     = (unsigned short*)(ws + 23592960);
  unsigned short* sa     = (unsigned short*)(ws + 29884416);

  prep_kernel<<<NB_CVT + NB_T1 + NB_T2, 256, 0, stream>>>(
      x, x_bf, Wkqv, wkqvT, Wproj, wprojT);

  // GEMM1: wave-independent 64x64 tiles -> 2304 blocks (exactly 9/CU)
  gemm_wi<N_KQV / 64, 0><<<2304, 64, 0, stream>>>(
      x_bf, wkqvT, bkqv, N_KQV, kb, qb, vT, nullptr);

  attn_kernel<<<dim3(64, BATCH * NH), 128, 0, stream>>>(qb, kb, vT, sa);

  // GEMM2: wave-independent 64x64 tiles -> 768 blocks (3/CU)
  gemm_wi<DMODEL / 64, 1><<<768, 64, 0, stream>>>(
      sa, wprojT, bproj, DMODEL, nullptr, nullptr, nullptr, out);
}